// Round 1
// baseline (1065.848 us; speedup 1.0000x reference)
//
#include <hip/hip_runtime.h>
#include <stdint.h>

#define E_    16
#define TOPK  2
#define D_    1024
#define H_    1024
#define SH_   2048
#define NTOK  4096
#define BK    32
#define LDSPAD 40   // 64B row (32 bf16) + 16B pad -> 2-way bank aliasing only (free)

typedef unsigned short u16;
typedef __attribute__((ext_vector_type(8))) __bf16 bf16x8;
typedef __attribute__((ext_vector_type(8))) u16    u16x8;
typedef __attribute__((ext_vector_type(4))) float  f32x4;

__device__ __forceinline__ u16 f2bf(float f) {
  union { float f; unsigned int u; } v; v.f = f;
  unsigned int u = v.u;
  return (u16)((u + 0x7fffu + ((u >> 16) & 1u)) >> 16);   // RN-even
}

__device__ __forceinline__ u16x8 pack8(float4 a, float4 b) {
  u16x8 r;
  r[0]=f2bf(a.x); r[1]=f2bf(a.y); r[2]=f2bf(a.z); r[3]=f2bf(a.w);
  r[4]=f2bf(b.x); r[5]=f2bf(b.y); r[6]=f2bf(b.z); r[7]=f2bf(b.w);
  return r;
}

// ---------------- x -> bf16 ----------------
__global__ __launch_bounds__(256) void prep_x(const float* __restrict__ x,
                                              u16* __restrict__ xb) {
  int i = blockIdx.x * 256 + threadIdx.x;          // group of 4 elements
  float4 f = ((const float4*)x)[i];
  u16x8 dummy; (void)dummy;
  ushort4 o; o.x=f2bf(f.x); o.y=f2bf(f.y); o.z=f2bf(f.z); o.w=f2bf(f.w);
  ((ushort4*)xb)[i] = o;
}

// ---------------- router: logits, softmax-top2, shared gate ----------------
__global__ __launch_bounds__(64) void router_k(
    const float* __restrict__ x, const float* __restrict__ gate_w,
    const float* __restrict__ shared_gate_w,
    int* __restrict__ topk_e, float* __restrict__ topk_w,
    float* __restrict__ sg, int* __restrict__ counts) {
  int t = blockIdx.x;
  int lane = threadIdx.x;
  float xv[16];
  #pragma unroll
  for (int i = 0; i < 16; i++) xv[i] = x[(size_t)t*D_ + i*64 + lane];
  float logit[E_];
  #pragma unroll
  for (int e = 0; e < E_; e++) {
    float p = 0.f;
    #pragma unroll
    for (int i = 0; i < 16; i++) p += xv[i] * gate_w[(size_t)e*D_ + i*64 + lane];
    #pragma unroll
    for (int s = 32; s; s >>= 1) p += __shfl_xor(p, s, 64);
    logit[e] = p;
  }
  float pg = 0.f;
  #pragma unroll
  for (int i = 0; i < 16; i++) pg += xv[i] * shared_gate_w[i*64 + lane];
  #pragma unroll
  for (int s = 32; s; s >>= 1) pg += __shfl_xor(pg, s, 64);

  if (lane == 0) {
    int i0 = 0; float l0 = logit[0];
    for (int e = 1; e < E_; e++) if (logit[e] > l0) { l0 = logit[e]; i0 = e; }
    int i1 = -1; float l1 = -3.4e38f;
    for (int e = 0; e < E_; e++) if (e != i0 && logit[e] > l1) { l1 = logit[e]; i1 = e; }
    float w0 = 1.f / (1.f + expf(l1 - l0));       // == p0/(p0+p1)
    topk_e[2*t] = i0; topk_e[2*t+1] = i1;
    topk_w[2*t] = w0; topk_w[2*t+1] = 1.f - w0;
    sg[t] = 1.f / (1.f + expf(-pg));
    atomicAdd(&counts[i0], 1);
    atomicAdd(&counts[i1], 1);
  }
}

__global__ void scan_k(const int* __restrict__ counts, int* __restrict__ offs) {
  if (threadIdx.x == 0) {
    int s = 0;
    for (int e = 0; e < E_; e++) { offs[e] = s; s += counts[e]; }
    offs[E_] = s;
  }
}

__global__ __launch_bounds__(256) void scatter_k(
    const int* __restrict__ topk_e, const float* __restrict__ topk_w,
    const int* __restrict__ offs, int* __restrict__ fill,
    int* __restrict__ tok_of, float* __restrict__ w_of) {
  int t = blockIdx.x * 256 + threadIdx.x;
  if (t >= NTOK) return;
  for (int k = 0; k < TOPK; k++) {
    int e = topk_e[2*t+k];
    int p = atomicAdd(&fill[e], 1);
    int slot = offs[e] + p;
    tok_of[slot] = t;
    w_of[slot]   = topk_w[2*t+k];
  }
}

// ---------------- fused gated up-projection: h = (x@W1^T) * silu(x@Wg^T) ----------------
// NT GEMM, 64x64 tile, BK=32, 4 waves each 32x32 via 2x2 mfma_f32_16x16x32_bf16
__global__ __launch_bounds__(256) void up_kernel(
    const u16* __restrict__ Xb,
    const float* __restrict__ Wg_all, const float* __restrict__ W1_all,
    u16* __restrict__ Hout, int H,
    const int* __restrict__ tok_of,
    const int* __restrict__ offs, const int* __restrict__ counts) {
  int e   = blockIdx.z;
  int cnt = counts ? counts[e] : NTOK;
  int m0  = blockIdx.x * 64;
  if (m0 >= cnt) return;
  int n0    = blockIdx.y * 64;
  int pbase = offs ? offs[e] : 0;
  const float* Wg = Wg_all + (size_t)e * H * D_;
  const float* W1 = W1_all + (size_t)e * H * D_;

  __shared__ u16 As[64 * LDSPAD];
  __shared__ u16 Gs[64 * LDSPAD];
  __shared__ u16 Us[64 * LDSPAD];

  int tid  = threadIdx.x;
  int lane = tid & 63, wave = tid >> 6;
  int wm = wave & 1, wn = wave >> 1;
  int l16 = lane & 15, quad = lane >> 4;

  int srow = tid >> 2;          // 0..63
  int skc  = (tid & 3) * 8;     // 0,8,16,24

  int mrow = m0 + srow; if (mrow >= cnt) mrow = cnt - 1;
  int tok  = tok_of ? tok_of[pbase + mrow] : mrow;
  const u16*   aptr = Xb + (size_t)tok * D_ + skc;
  const float* gptr = Wg + (size_t)(n0 + srow) * D_ + skc;
  const float* uptr = W1 + (size_t)(n0 + srow) * D_ + skc;

  f32x4 accg[2][2], accu[2][2];
  f32x4 zero = {0.f, 0.f, 0.f, 0.f};
  #pragma unroll
  for (int i = 0; i < 2; i++)
    #pragma unroll
    for (int j = 0; j < 2; j++) { accg[i][j] = zero; accu[i][j] = zero; }

  for (int k0 = 0; k0 < D_; k0 += BK) {
    uint4  av = *(const uint4*)(aptr + k0);
    float4 g0 = *(const float4*)(gptr + k0);
    float4 g1 = *(const float4*)(gptr + k0 + 4);
    float4 u0 = *(const float4*)(uptr + k0);
    float4 u1 = *(const float4*)(uptr + k0 + 4);
    __syncthreads();
    *(uint4*)&As[srow*LDSPAD + skc] = av;
    *(u16x8*)&Gs[srow*LDSPAD + skc] = pack8(g0, g1);
    *(u16x8*)&Us[srow*LDSPAD + skc] = pack8(u0, u1);
    __syncthreads();

    bf16x8 af[2], gf[2], uf[2];
    #pragma unroll
    for (int i = 0; i < 2; i++) {
      af[i] = *(const bf16x8*)&As[(wm*32 + i*16 + l16)*LDSPAD + quad*8];
      gf[i] = *(const bf16x8*)&Gs[(wn*32 + i*16 + l16)*LDSPAD + quad*8];
      uf[i] = *(const bf16x8*)&Us[(wn*32 + i*16 + l16)*LDSPAD + quad*8];
    }
    #pragma unroll
    for (int i = 0; i < 2; i++)
      #pragma unroll
      for (int j = 0; j < 2; j++) {
        accg[i][j] = __builtin_amdgcn_mfma_f32_16x16x32_bf16(af[i], gf[j], accg[i][j], 0, 0, 0);
        accu[i][j] = __builtin_amdgcn_mfma_f32_16x16x32_bf16(af[i], uf[j], accu[i][j], 0, 0, 0);
      }
  }

  // epilogue: h = u * silu(g), bf16 store (C/D map: col=lane&15, row=quad*4+reg)
  #pragma unroll
  for (int i = 0; i < 2; i++) {
    #pragma unroll
    for (int r = 0; r < 4; r++) {
      int m = m0 + wm*32 + i*16 + quad*4 + r;
      if (m < cnt) {
        size_t prow = (size_t)(pbase + m) * H;
        #pragma unroll
        for (int j = 0; j < 2; j++) {
          int n = n0 + wn*32 + j*16 + l16;
          float g = accg[i][j][r];
          float u = accu[i][j][r];
          float hv = u * (g / (1.f + expf(-g)));
          Hout[prow + n] = f2bf(hv);
        }
      }
    }
  }
}

// ---------------- down-projection: out[tok] += scale * (h @ W2^T) ----------------
__global__ __launch_bounds__(256) void down_kernel(
    const u16* __restrict__ Hbuf, int K,
    const float* __restrict__ W2_all,
    float* __restrict__ out,
    const int* __restrict__ tok_of, const float* __restrict__ scale,
    const int* __restrict__ offs, const int* __restrict__ counts) {
  int e   = blockIdx.z;
  int cnt = counts ? counts[e] : NTOK;
  int m0  = blockIdx.x * 64;
  if (m0 >= cnt) return;
  int n0    = blockIdx.y * 64;
  int pbase = offs ? offs[e] : 0;
  const float* W2 = W2_all + (size_t)e * D_ * K;

  __shared__ u16 As[64 * LDSPAD];
  __shared__ u16 Ws[64 * LDSPAD];

  int tid  = threadIdx.x;
  int lane = tid & 63, wave = tid >> 6;
  int wm = wave & 1, wn = wave >> 1;
  int l16 = lane & 15, quad = lane >> 4;

  int srow = tid >> 2;
  int skc  = (tid & 3) * 8;

  int arow = m0 + srow; if (arow >= cnt) arow = cnt - 1;
  const u16*   aptr = Hbuf + (size_t)(pbase + arow) * K + skc;
  const float* wptr = W2 + (size_t)(n0 + srow) * K + skc;

  f32x4 acc[2][2];
  f32x4 zero = {0.f, 0.f, 0.f, 0.f};
  #pragma unroll
  for (int i = 0; i < 2; i++)
    #pragma unroll
    for (int j = 0; j < 2; j++) acc[i][j] = zero;

  for (int k0 = 0; k0 < K; k0 += BK) {
    uint4  av = *(const uint4*)(aptr + k0);
    float4 w0v = *(const float4*)(wptr + k0);
    float4 w1v = *(const float4*)(wptr + k0 + 4);
    __syncthreads();
    *(uint4*)&As[srow*LDSPAD + skc] = av;
    *(u16x8*)&Ws[srow*LDSPAD + skc] = pack8(w0v, w1v);
    __syncthreads();

    bf16x8 af[2], bf[2];
    #pragma unroll
    for (int i = 0; i < 2; i++) {
      af[i] = *(const bf16x8*)&As[(wm*32 + i*16 + l16)*LDSPAD + quad*8];
      bf[i] = *(const bf16x8*)&Ws[(wn*32 + i*16 + l16)*LDSPAD + quad*8];
    }
    #pragma unroll
    for (int i = 0; i < 2; i++)
      #pragma unroll
      for (int j = 0; j < 2; j++)
        acc[i][j] = __builtin_amdgcn_mfma_f32_16x16x32_bf16(af[i], bf[j], acc[i][j], 0, 0, 0);
  }

  #pragma unroll
  for (int i = 0; i < 2; i++) {
    #pragma unroll
    for (int r = 0; r < 4; r++) {
      int m = m0 + wm*32 + i*16 + quad*4 + r;
      if (m < cnt) {
        int p   = pbase + m;
        int tok = tok_of ? tok_of[p] : p;
        float sc = scale[p];
        #pragma unroll
        for (int j = 0; j < 2; j++) {
          int n = n0 + wn*32 + j*16 + l16;
          atomicAdd(&out[(size_t)tok * D_ + n], sc * acc[i][j][r]);
        }
      }
    }
  }
}

extern "C" void kernel_launch(void* const* d_in, const int* in_sizes, int n_in,
                              void* d_out, int out_size, void* d_ws, size_t ws_size,
                              hipStream_t stream) {
  const float* x      = (const float*)d_in[0];
  const float* gate_w = (const float*)d_in[1];
  const float* w_gate = (const float*)d_in[2];
  const float* w1     = (const float*)d_in[3];
  const float* w2     = (const float*)d_in[4];
  const float* sh_wg  = (const float*)d_in[5];
  const float* sh_w1  = (const float*)d_in[6];
  const float* sh_w2  = (const float*)d_in[7];
  const float* sh_gw  = (const float*)d_in[8];
  float* out = (float*)d_out;

  char* ws = (char*)d_ws;
  size_t off = 0;
  u16* xb    = (u16*)(ws + off); off += (size_t)NTOK * D_ * 2;        // 8 MB
  u16* h_exp = (u16*)(ws + off); off += (size_t)NTOK * TOPK * H_ * 2; // 16 MB
  u16* h_sh  = (u16*)(ws + off); off += (size_t)NTOK * SH_ * 2;      // 16 MB
  int*   tok_of = (int*)  (ws + off); off += NTOK * TOPK * 4;
  float* w_of   = (float*)(ws + off); off += NTOK * TOPK * 4;
  float* sg     = (float*)(ws + off); off += NTOK * 4;
  int*   topk_e = (int*)  (ws + off); off += NTOK * TOPK * 4;
  float* topk_w = (float*)(ws + off); off += NTOK * TOPK * 4;
  int*   counts = (int*)  (ws + off); off += 64;
  int*   offs   = (int*)  (ws + off); off += 128;
  int*   fill   = (int*)  (ws + off); off += 64;

  hipMemsetAsync(out, 0, (size_t)out_size * 4, stream);
  hipMemsetAsync(counts, 0, 256, stream);   // counts + offs + fill

  prep_x<<<dim3((NTOK * D_ / 4) / 256), 256, 0, stream>>>(x, xb);
  router_k<<<dim3(NTOK), 64, 0, stream>>>(x, gate_w, sh_gw, topk_e, topk_w, sg, counts);
  scan_k<<<dim3(1), 64, 0, stream>>>(counts, offs);
  scatter_k<<<dim3((NTOK + 255) / 256), 256, 0, stream>>>(topk_e, topk_w, offs, fill, tok_of, w_of);

  // experts
  up_kernel<<<dim3(NTOK/64, H_/64, E_), 256, 0, stream>>>(
      xb, w_gate, w1, h_exp, H_, tok_of, offs, counts);
  down_kernel<<<dim3(NTOK/64, D_/64, E_), 256, 0, stream>>>(
      h_exp, H_, w2, out, tok_of, w_of, offs, counts);

  // shared expert (identity token list, sigmoid gate scale)
  up_kernel<<<dim3(NTOK/64, SH_/64, 1), 256, 0, stream>>>(
      xb, sh_wg, sh_w1, h_sh, SH_, nullptr, nullptr, nullptr);
  down_kernel<<<dim3(NTOK/64, D_/64, 1), 256, 0, stream>>>(
      h_sh, SH_, sh_w2, out, nullptr, sg, nullptr, nullptr);

  (void)in_sizes; (void)n_in; (void)ws_size;
}

// Round 2
// 1010.742 us; speedup vs baseline: 1.0545x; 1.0545x over previous
//
#include <hip/hip_runtime.h>
#include <stdint.h>

#define E_    16
#define TOPK  2
#define D_    1024
#define H_    1024
#define SH_   2048
#define NTOK  4096

typedef unsigned short u16;
typedef __attribute__((ext_vector_type(8))) __bf16 bf16x8;
typedef __attribute__((ext_vector_type(4))) float  f32x4;

__device__ __forceinline__ u16 f2bf(float f) {
  union { float f; unsigned int u; } v; v.f = f;
  unsigned int u = v.u;
  return (u16)((u + 0x7fffu + ((u >> 16) & 1u)) >> 16);   // RN-even
}

// async 16B global->LDS (wave-uniform LDS base + lane*16 ordering is enforced
// by construction: lds offset == wave*1024 + lane*16 for the staging index map)
__device__ __forceinline__ void async16(const void* g, void* l) {
  __builtin_amdgcn_global_load_lds(
      (const __attribute__((address_space(1))) unsigned int*)g,
      (__attribute__((address_space(3))) unsigned int*)l,
      16, 0, 0);
}

// ---------------- fp32 -> bf16 converters ----------------
__global__ __launch_bounds__(256) void cvt_k(const float* __restrict__ src,
                                             u16* __restrict__ dst) {
  int i = blockIdx.x * 256 + threadIdx.x;      // one float4 per thread
  float4 f = ((const float4*)src)[i];
  ushort4 o; o.x = f2bf(f.x); o.y = f2bf(f.y); o.z = f2bf(f.z); o.w = f2bf(f.w);
  ((ushort4*)dst)[i] = o;
}

// ---------------- router: logits, softmax-top2, shared gate ----------------
__global__ __launch_bounds__(64) void router_k(
    const float* __restrict__ x, const float* __restrict__ gate_w,
    const float* __restrict__ shared_gate_w,
    int* __restrict__ topk_e, float* __restrict__ topk_w,
    float* __restrict__ sg, int* __restrict__ counts) {
  int t = blockIdx.x;
  int lane = threadIdx.x;
  float xv[16];
  #pragma unroll
  for (int i = 0; i < 16; i++) xv[i] = x[(size_t)t*D_ + i*64 + lane];
  float logit[E_];
  #pragma unroll
  for (int e = 0; e < E_; e++) {
    float p = 0.f;
    #pragma unroll
    for (int i = 0; i < 16; i++) p += xv[i] * gate_w[(size_t)e*D_ + i*64 + lane];
    #pragma unroll
    for (int s = 32; s; s >>= 1) p += __shfl_xor(p, s, 64);
    logit[e] = p;
  }
  float pg = 0.f;
  #pragma unroll
  for (int i = 0; i < 16; i++) pg += xv[i] * shared_gate_w[i*64 + lane];
  #pragma unroll
  for (int s = 32; s; s >>= 1) pg += __shfl_xor(pg, s, 64);

  if (lane == 0) {
    int i0 = 0; float l0 = logit[0];
    for (int e = 1; e < E_; e++) if (logit[e] > l0) { l0 = logit[e]; i0 = e; }
    int i1 = -1; float l1 = -3.4e38f;
    for (int e = 0; e < E_; e++) if (e != i0 && logit[e] > l1) { l1 = logit[e]; i1 = e; }
    float w0 = 1.f / (1.f + expf(l1 - l0));       // == p0/(p0+p1)
    topk_e[2*t] = i0; topk_e[2*t+1] = i1;
    topk_w[2*t] = w0; topk_w[2*t+1] = 1.f - w0;
    sg[t] = 1.f / (1.f + expf(-pg));
    atomicAdd(&counts[i0], 1);
    atomicAdd(&counts[i1], 1);
  }
}

__global__ void scan_k(const int* __restrict__ counts, int* __restrict__ offs) {
  if (threadIdx.x == 0) {
    int s = 0;
    for (int e = 0; e < E_; e++) { offs[e] = s; s += counts[e]; }
    offs[E_] = s;
  }
}

__global__ __launch_bounds__(256) void scatter_k(
    const int* __restrict__ topk_e, const float* __restrict__ topk_w,
    const int* __restrict__ offs, int* __restrict__ fill,
    int* __restrict__ tok_of, float* __restrict__ w_of) {
  int t = blockIdx.x * 256 + threadIdx.x;
  if (t >= NTOK) return;
  for (int k = 0; k < TOPK; k++) {
    int e = topk_e[2*t+k];
    int p = atomicAdd(&fill[e], 1);
    int slot = offs[e] + p;
    tok_of[slot] = t;
    w_of[slot]   = topk_w[2*t+k];
  }
}

// ---------------- fused gated up-projection: h = (x@W1^T) * silu(x@Wg^T) ----
// NT GEMM, 128x128 tile, BK=32, 4 waves each 64x64 via 4x4 mfma_f32_16x16x32_bf16
// Staging: global_load_lds width-16 into unpadded [128][32] bf16 (LDS off = wave*1024+lane*16)
__global__ __launch_bounds__(256, 2) void up_kernel(
    const u16* __restrict__ Xb,
    const u16* __restrict__ Wg_all, const u16* __restrict__ W1_all,
    u16* __restrict__ Hout, int H,
    const int* __restrict__ tok_of,
    const int* __restrict__ offs, const int* __restrict__ counts) {
  int e   = blockIdx.z;
  int cnt = counts ? counts[e] : NTOK;
  int m0  = blockIdx.x * 128;
  if (m0 >= cnt) return;
  int n0    = blockIdx.y * 128;
  int pbase = offs ? offs[e] : 0;
  const u16* Wg = Wg_all + (size_t)e * H * D_;
  const u16* W1 = W1_all + (size_t)e * H * D_;

  __shared__ u16 As[128*32];
  __shared__ u16 Gs[128*32];
  __shared__ u16 Us[128*32];

  int tid  = threadIdx.x;
  int lane = tid & 63, wave = tid >> 6;
  int wm = wave & 1, wn = wave >> 1;
  int l16 = lane & 15, quad = lane >> 4;

  int rs = tid >> 2;          // staging row 0..63 (and +64)
  int cs = (tid & 3) * 8;     // staging col (elements)

  int gm0 = m0 + rs;      if (gm0 >= cnt) gm0 = cnt - 1;
  int gm1 = m0 + rs + 64; if (gm1 >= cnt) gm1 = cnt - 1;
  int tok0 = tok_of ? tok_of[pbase + gm0] : gm0;
  int tok1 = tok_of ? tok_of[pbase + gm1] : gm1;
  const u16* pa0 = Xb + (size_t)tok0 * D_ + cs;
  const u16* pa1 = Xb + (size_t)tok1 * D_ + cs;
  const u16* pg0 = Wg + (size_t)(n0 + rs) * D_ + cs;
  const u16* pg1 = pg0 + (size_t)64 * D_;
  const u16* pu0 = W1 + (size_t)(n0 + rs) * D_ + cs;
  const u16* pu1 = pu0 + (size_t)64 * D_;
  u16* lA0 = &As[rs*32 + cs]; u16* lA1 = &As[(rs+64)*32 + cs];
  u16* lG0 = &Gs[rs*32 + cs]; u16* lG1 = &Gs[(rs+64)*32 + cs];
  u16* lU0 = &Us[rs*32 + cs]; u16* lU1 = &Us[(rs+64)*32 + cs];

  f32x4 accg[4][4], accu[4][4];
  f32x4 zero = {0.f, 0.f, 0.f, 0.f};
  #pragma unroll
  for (int i = 0; i < 4; i++)
    #pragma unroll
    for (int j = 0; j < 4; j++) { accg[i][j] = zero; accu[i][j] = zero; }

  for (int k0 = 0; k0 < D_; k0 += 32) {
    async16(pa0 + k0, lA0); async16(pa1 + k0, lA1);
    async16(pg0 + k0, lG0); async16(pg1 + k0, lG1);
    async16(pu0 + k0, lU0); async16(pu1 + k0, lU1);
    __syncthreads();                       // drains vmcnt before ds_read

    bf16x8 af[4], gf[4], uf[4];
    #pragma unroll
    for (int i = 0; i < 4; i++) {
      af[i] = *(const bf16x8*)&As[(wm*64 + i*16 + l16)*32 + quad*8];
      gf[i] = *(const bf16x8*)&Gs[(wn*64 + i*16 + l16)*32 + quad*8];
      uf[i] = *(const bf16x8*)&Us[(wn*64 + i*16 + l16)*32 + quad*8];
    }
    #pragma unroll
    for (int i = 0; i < 4; i++)
      #pragma unroll
      for (int j = 0; j < 4; j++) {
        accg[i][j] = __builtin_amdgcn_mfma_f32_16x16x32_bf16(af[i], gf[j], accg[i][j], 0, 0, 0);
        accu[i][j] = __builtin_amdgcn_mfma_f32_16x16x32_bf16(af[i], uf[j], accu[i][j], 0, 0, 0);
      }
    __syncthreads();                       // all waves done reading LDS
  }

  // epilogue: h = u * silu(g)  (C/D map: col=lane&15, row=quad*4+reg — verified R1)
  #pragma unroll
  for (int i = 0; i < 4; i++) {
    #pragma unroll
    for (int r = 0; r < 4; r++) {
      int m = m0 + wm*64 + i*16 + quad*4 + r;
      if (m < cnt) {
        size_t prow = (size_t)(pbase + m) * H;
        #pragma unroll
        for (int j = 0; j < 4; j++) {
          int n = n0 + wn*64 + j*16 + l16;
          float g = accg[i][j][r];
          float u = accu[i][j][r];
          Hout[prow + n] = f2bf(u * (g / (1.f + expf(-g))));
        }
      }
    }
  }
}

// ---------------- down-projection: out[tok] (+)= scale * (h @ W2^T) ---------
__global__ __launch_bounds__(256, 3) void down_kernel(
    const u16* __restrict__ Hbuf, int K,
    const u16* __restrict__ W2_all,
    float* __restrict__ out,
    const int* __restrict__ tok_of, const float* __restrict__ scale,
    const int* __restrict__ offs, const int* __restrict__ counts,
    int atomic_mode) {
  int e   = blockIdx.z;
  int cnt = counts ? counts[e] : NTOK;
  int m0  = blockIdx.x * 128;
  if (m0 >= cnt) return;
  int n0    = blockIdx.y * 128;
  int pbase = offs ? offs[e] : 0;
  const u16* W2 = W2_all + (size_t)e * D_ * K;

  __shared__ u16 As[128*32];
  __shared__ u16 Bs[128*32];

  int tid  = threadIdx.x;
  int lane = tid & 63, wave = tid >> 6;
  int wm = wave & 1, wn = wave >> 1;
  int l16 = lane & 15, quad = lane >> 4;

  int rs = tid >> 2;
  int cs = (tid & 3) * 8;

  int gm0 = m0 + rs;      if (gm0 >= cnt) gm0 = cnt - 1;
  int gm1 = m0 + rs + 64; if (gm1 >= cnt) gm1 = cnt - 1;
  const u16* pa0 = Hbuf + (size_t)(pbase + gm0) * K + cs;
  const u16* pa1 = Hbuf + (size_t)(pbase + gm1) * K + cs;
  const u16* pb0 = W2 + (size_t)(n0 + rs) * K + cs;
  const u16* pb1 = pb0 + (size_t)64 * K;
  u16* lA0 = &As[rs*32 + cs]; u16* lA1 = &As[(rs+64)*32 + cs];
  u16* lB0 = &Bs[rs*32 + cs]; u16* lB1 = &Bs[(rs+64)*32 + cs];

  f32x4 acc[4][4];
  f32x4 zero = {0.f, 0.f, 0.f, 0.f};
  #pragma unroll
  for (int i = 0; i < 4; i++)
    #pragma unroll
    for (int j = 0; j < 4; j++) acc[i][j] = zero;

  for (int k0 = 0; k0 < K; k0 += 32) {
    async16(pa0 + k0, lA0); async16(pa1 + k0, lA1);
    async16(pb0 + k0, lB0); async16(pb1 + k0, lB1);
    __syncthreads();

    bf16x8 af[4], bfr[4];
    #pragma unroll
    for (int i = 0; i < 4; i++) {
      af[i]  = *(const bf16x8*)&As[(wm*64 + i*16 + l16)*32 + quad*8];
      bfr[i] = *(const bf16x8*)&Bs[(wn*64 + i*16 + l16)*32 + quad*8];
    }
    #pragma unroll
    for (int i = 0; i < 4; i++)
      #pragma unroll
      for (int j = 0; j < 4; j++)
        acc[i][j] = __builtin_amdgcn_mfma_f32_16x16x32_bf16(af[i], bfr[j], acc[i][j], 0, 0, 0);
    __syncthreads();
  }

  #pragma unroll
  for (int i = 0; i < 4; i++) {
    #pragma unroll
    for (int r = 0; r < 4; r++) {
      int m = m0 + wm*64 + i*16 + quad*4 + r;
      if (m < cnt) {
        int p   = pbase + m;
        int tok = tok_of ? tok_of[p] : p;
        float sc = scale[p];
        if (atomic_mode) {
          #pragma unroll
          for (int j = 0; j < 4; j++) {
            int n = n0 + wn*64 + j*16 + l16;
            atomicAdd(&out[(size_t)tok * D_ + n], sc * acc[i][j][r]);
          }
        } else {
          #pragma unroll
          for (int j = 0; j < 4; j++) {
            int n = n0 + wn*64 + j*16 + l16;
            out[(size_t)tok * D_ + n] = sc * acc[i][j][r];
          }
        }
      }
    }
  }
}

extern "C" void kernel_launch(void* const* d_in, const int* in_sizes, int n_in,
                              void* d_out, int out_size, void* d_ws, size_t ws_size,
                              hipStream_t stream) {
  const float* x      = (const float*)d_in[0];
  const float* gate_w = (const float*)d_in[1];
  const float* w_gate = (const float*)d_in[2];
  const float* w1     = (const float*)d_in[3];
  const float* w2     = (const float*)d_in[4];
  const float* sh_wg  = (const float*)d_in[5];
  const float* sh_w1  = (const float*)d_in[6];
  const float* sh_w2  = (const float*)d_in[7];
  const float* sh_gw  = (const float*)d_in[8];
  float* out = (float*)d_out;

  char* ws = (char*)d_ws;
  size_t off = 0;
  u16* xb    = (u16*)(ws + off); off += (size_t)NTOK * D_ * 2;          // 8 MB
  u16* h_exp = (u16*)(ws + off); off += (size_t)NTOK * TOPK * H_ * 2;   // 16 MB
  u16* h_sh  = (u16*)(ws + off); off += (size_t)NTOK * SH_ * 2;         // 16 MB
  u16* wb_g  = (u16*)(ws + off); off += (size_t)E_ * H_ * D_ * 2;       // 32 MB
  u16* wb_1  = (u16*)(ws + off); off += (size_t)E_ * H_ * D_ * 2;       // 32 MB
  u16* wb_2  = (u16*)(ws + off); off += (size_t)E_ * D_ * H_ * 2;       // 32 MB
  u16* sb_g  = (u16*)(ws + off); off += (size_t)SH_ * D_ * 2;           // 4 MB
  u16* sb_1  = (u16*)(ws + off); off += (size_t)SH_ * D_ * 2;           // 4 MB
  u16* sb_2  = (u16*)(ws + off); off += (size_t)D_ * SH_ * 2;           // 4 MB
  int*   tok_of = (int*)  (ws + off); off += NTOK * TOPK * 4;
  float* w_of   = (float*)(ws + off); off += NTOK * TOPK * 4;
  float* sg     = (float*)(ws + off); off += NTOK * 4;
  int*   topk_e = (int*)  (ws + off); off += NTOK * TOPK * 4;
  float* topk_w = (float*)(ws + off); off += NTOK * TOPK * 4;
  int*   counts = (int*)  (ws + off); off += 64;
  int*   offs   = (int*)  (ws + off); off += 128;
  int*   fill   = (int*)  (ws + off); off += 64;

  hipMemsetAsync(counts, 0, 256, stream);   // counts + offs + fill

  // x -> bf16 ; weights -> bf16
  cvt_k<<<dim3(NTOK * D_ / 1024), 256, 0, stream>>>(x, xb);
  cvt_k<<<dim3(E_ * H_ * D_ / 1024), 256, 0, stream>>>(w_gate, wb_g);
  cvt_k<<<dim3(E_ * H_ * D_ / 1024), 256, 0, stream>>>(w1, wb_1);
  cvt_k<<<dim3(E_ * D_ * H_ / 1024), 256, 0, stream>>>(w2, wb_2);
  cvt_k<<<dim3(SH_ * D_ / 1024), 256, 0, stream>>>(sh_wg, sb_g);
  cvt_k<<<dim3(SH_ * D_ / 1024), 256, 0, stream>>>(sh_w1, sb_1);
  cvt_k<<<dim3(D_ * SH_ / 1024), 256, 0, stream>>>(sh_w2, sb_2);

  router_k<<<dim3(NTOK), 64, 0, stream>>>(x, gate_w, sh_gw, topk_e, topk_w, sg, counts);
  scan_k<<<dim3(1), 64, 0, stream>>>(counts, offs);
  scatter_k<<<dim3((NTOK + 255) / 256), 256, 0, stream>>>(topk_e, topk_w, offs, fill, tok_of, w_of);

  // shared expert first: its down-projection STOREs (covers all of out, no memset)
  up_kernel<<<dim3(NTOK/128, SH_/128, 1), 256, 0, stream>>>(
      xb, sb_g, sb_1, h_sh, SH_, nullptr, nullptr, nullptr);
  down_kernel<<<dim3(NTOK/128, D_/128, 1), 256, 0, stream>>>(
      h_sh, SH_, sb_2, out, nullptr, sg, nullptr, nullptr, /*atomic=*/0);

  // routed experts: accumulate on top with atomics
  up_kernel<<<dim3(NTOK/128, H_/128, E_), 256, 0, stream>>>(
      xb, wb_g, wb_1, h_exp, H_, tok_of, offs, counts);
  down_kernel<<<dim3(NTOK/128, D_/128, E_), 256, 0, stream>>>(
      h_exp, H_, wb_2, out, tok_of, w_of, offs, counts, /*atomic=*/1);

  (void)in_sizes; (void)n_in; (void)ws_size;
}

// Round 3
// 649.959 us; speedup vs baseline: 1.6399x; 1.5551x over previous
//
#include <hip/hip_runtime.h>
#include <stdint.h>

#define E_    16
#define TOPK  2
#define D_    1024
#define H_    1024
#define SH_   2048
#define NTOK  4096
#define LROW  40      // LDS row pitch in u16: 32 payload + 8 pad -> only 2-way bank aliasing (free)
#define NDESC 80      // max expert chunks: 8192/128 + 16 partials

typedef unsigned short u16;
typedef __attribute__((ext_vector_type(8))) __bf16 bf16x8;
typedef __attribute__((ext_vector_type(4))) float  f32x4;

__device__ __forceinline__ u16 f2bf(float f) {
  union { float f; unsigned int u; } v; v.f = f;
  unsigned int u = v.u;
  return (u16)((u + 0x7fffu + ((u >> 16) & 1u)) >> 16);   // RN-even
}

// ---------------- fp32 -> bf16 converter ----------------
__global__ __launch_bounds__(256) void cvt_k(const float* __restrict__ src,
                                             u16* __restrict__ dst) {
  int i = blockIdx.x * 256 + threadIdx.x;      // one float4 per thread
  float4 f = ((const float4*)src)[i];
  ushort4 o; o.x = f2bf(f.x); o.y = f2bf(f.y); o.z = f2bf(f.z); o.w = f2bf(f.w);
  ((ushort4*)dst)[i] = o;
}

// ---------------- router ----------------
__global__ __launch_bounds__(64) void router_k(
    const float* __restrict__ x, const float* __restrict__ gate_w,
    const float* __restrict__ shared_gate_w,
    int* __restrict__ topk_e, float* __restrict__ topk_w,
    float* __restrict__ sg, int* __restrict__ counts) {
  int t = blockIdx.x;
  int lane = threadIdx.x;
  float xv[16];
  #pragma unroll
  for (int i = 0; i < 16; i++) xv[i] = x[(size_t)t*D_ + i*64 + lane];
  float logit[E_];
  #pragma unroll
  for (int e = 0; e < E_; e++) {
    float p = 0.f;
    #pragma unroll
    for (int i = 0; i < 16; i++) p += xv[i] * gate_w[(size_t)e*D_ + i*64 + lane];
    #pragma unroll
    for (int s = 32; s; s >>= 1) p += __shfl_xor(p, s, 64);
    logit[e] = p;
  }
  float pg = 0.f;
  #pragma unroll
  for (int i = 0; i < 16; i++) pg += xv[i] * shared_gate_w[i*64 + lane];
  #pragma unroll
  for (int s = 32; s; s >>= 1) pg += __shfl_xor(pg, s, 64);

  if (lane == 0) {
    int i0 = 0; float l0 = logit[0];
    for (int e = 1; e < E_; e++) if (logit[e] > l0) { l0 = logit[e]; i0 = e; }
    int i1 = -1; float l1 = -3.4e38f;
    for (int e = 0; e < E_; e++) if (e != i0 && logit[e] > l1) { l1 = logit[e]; i1 = e; }
    float w0 = 1.f / (1.f + expf(l1 - l0));
    topk_e[2*t] = i0; topk_e[2*t+1] = i1;
    topk_w[2*t] = w0; topk_w[2*t+1] = 1.f - w0;
    sg[t] = 1.f / (1.f + expf(-pg));
    atomicAdd(&counts[i0], 1);
    atomicAdd(&counts[i1], 1);
  }
}

// prefix scan + compact chunk-descriptor table (chunk -> expert, m0)
__global__ void scan_k(const int* __restrict__ counts, int* __restrict__ offs,
                       int* __restrict__ desc_e, int* __restrict__ desc_m) {
  if (threadIdx.x == 0) {
    int s = 0, n = 0;
    for (int e = 0; e < E_; e++) {
      offs[e] = s;
      for (int m0 = 0; m0 < counts[e]; m0 += 128) {
        desc_e[n] = e; desc_m[n] = m0; n++;
      }
      s += counts[e];
    }
    offs[E_] = s;
    for (; n < NDESC; n++) { desc_e[n] = -1; desc_m[n] = 0; }
  }
}

__global__ __launch_bounds__(256) void scatter_k(
    const int* __restrict__ topk_e, const float* __restrict__ topk_w,
    const int* __restrict__ offs, int* __restrict__ fill,
    int* __restrict__ tok_of, float* __restrict__ w_of) {
  int t = blockIdx.x * 256 + threadIdx.x;
  if (t >= NTOK) return;
  for (int k = 0; k < TOPK; k++) {
    int e = topk_e[2*t+k];
    int p = atomicAdd(&fill[e], 1);
    int slot = offs[e] + p;
    tok_of[slot] = t;
    w_of[slot]   = topk_w[2*t+k];
  }
}

// ---------------- fused gated up-projection: h = (x@W1^T) * silu(x@Wg^T) ----
// NT GEMM, 128x128 tile, BK=32, explicit global->VGPR->ds_write staging with
// next-tile VGPR prefetch overlapping MFMA (m93 structure, bf16 => no repack).
__global__ __launch_bounds__(256, 2) void up_kernel(
    const u16* __restrict__ Xb,
    const u16* __restrict__ Wg_all, const u16* __restrict__ W1_all,
    u16* __restrict__ Hout, int H,
    const int* __restrict__ tok_of,
    const int* __restrict__ offs, const int* __restrict__ counts,
    const int* __restrict__ desc_e, const int* __restrict__ desc_m) {
  int e, m0, cnt, pbase;
  if (desc_e) {
    e = desc_e[blockIdx.x];
    if (e < 0) return;
    m0 = desc_m[blockIdx.x];
    cnt = counts[e]; pbase = offs[e];
  } else {
    e = 0; m0 = blockIdx.x * 128; cnt = NTOK; pbase = 0;
  }
  int n0 = blockIdx.y * 128;
  const u16* Wg = Wg_all + (size_t)e * H * D_;
  const u16* W1 = W1_all + (size_t)e * H * D_;

  __shared__ u16 As[128 * LROW];
  __shared__ u16 Gs[128 * LROW];
  __shared__ u16 Us[128 * LROW];

  int tid  = threadIdx.x;
  int lane = tid & 63, wave = tid >> 6;
  int wm = wave & 1, wn = wave >> 1;
  int l16 = lane & 15, quad = lane >> 4;

  int rs = tid >> 2;          // staging row 0..63 (and +64)
  int cs = (tid & 3) * 8;     // staging col (elements)

  int gm0 = m0 + rs;      if (gm0 >= cnt) gm0 = cnt - 1;
  int gm1 = m0 + rs + 64; if (gm1 >= cnt) gm1 = cnt - 1;
  int tok0 = tok_of ? tok_of[pbase + gm0] : gm0;
  int tok1 = tok_of ? tok_of[pbase + gm1] : gm1;
  const u16* pa0 = Xb + (size_t)tok0 * D_ + cs;
  const u16* pa1 = Xb + (size_t)tok1 * D_ + cs;
  const u16* pg0 = Wg + (size_t)(n0 + rs) * D_ + cs;
  const u16* pg1 = pg0 + (size_t)64 * D_;
  const u16* pu0 = W1 + (size_t)(n0 + rs) * D_ + cs;
  const u16* pu1 = pu0 + (size_t)64 * D_;
  uint4* lA0 = (uint4*)&As[rs*LROW + cs]; uint4* lA1 = (uint4*)&As[(rs+64)*LROW + cs];
  uint4* lG0 = (uint4*)&Gs[rs*LROW + cs]; uint4* lG1 = (uint4*)&Gs[(rs+64)*LROW + cs];
  uint4* lU0 = (uint4*)&Us[rs*LROW + cs]; uint4* lU1 = (uint4*)&Us[(rs+64)*LROW + cs];

  f32x4 accg[4][4], accu[4][4];
  f32x4 zero = {0.f, 0.f, 0.f, 0.f};
  #pragma unroll
  for (int i = 0; i < 4; i++)
    #pragma unroll
    for (int j = 0; j < 4; j++) { accg[i][j] = zero; accu[i][j] = zero; }

  uint4 ra0 = *(const uint4*)pa0, ra1 = *(const uint4*)pa1;
  uint4 rg0 = *(const uint4*)pg0, rg1 = *(const uint4*)pg1;
  uint4 ru0 = *(const uint4*)pu0, ru1 = *(const uint4*)pu1;

  for (int k0 = 0; k0 < D_; k0 += 32) {
    __syncthreads();                 // prev iter's LDS reads done
    *lA0 = ra0; *lA1 = ra1;
    *lG0 = rg0; *lG1 = rg1;
    *lU0 = ru0; *lU1 = ru1;
    __syncthreads();                 // tile visible to all waves
    if (k0 + 32 < D_) {              // prefetch next tile; overlaps MFMA below
      pa0 += 32; pa1 += 32; pg0 += 32; pg1 += 32; pu0 += 32; pu1 += 32;
      ra0 = *(const uint4*)pa0; ra1 = *(const uint4*)pa1;
      rg0 = *(const uint4*)pg0; rg1 = *(const uint4*)pg1;
      ru0 = *(const uint4*)pu0; ru1 = *(const uint4*)pu1;
    }

    bf16x8 af[4], gf[4], uf[4];
    #pragma unroll
    for (int i = 0; i < 4; i++) {
      af[i] = *(const bf16x8*)&As[(wm*64 + i*16 + l16)*LROW + quad*8];
      gf[i] = *(const bf16x8*)&Gs[(wn*64 + i*16 + l16)*LROW + quad*8];
      uf[i] = *(const bf16x8*)&Us[(wn*64 + i*16 + l16)*LROW + quad*8];
    }
    #pragma unroll
    for (int i = 0; i < 4; i++)
      #pragma unroll
      for (int j = 0; j < 4; j++) {
        accg[i][j] = __builtin_amdgcn_mfma_f32_16x16x32_bf16(af[i], gf[j], accg[i][j], 0, 0, 0);
        accu[i][j] = __builtin_amdgcn_mfma_f32_16x16x32_bf16(af[i], uf[j], accu[i][j], 0, 0, 0);
      }
  }

  // epilogue: h = u * silu(g)  (C/D map: col=lane&15, row=quad*4+reg — verified)
  #pragma unroll
  for (int i = 0; i < 4; i++) {
    #pragma unroll
    for (int r = 0; r < 4; r++) {
      int m = m0 + wm*64 + i*16 + quad*4 + r;
      if (m < cnt) {
        size_t prow = (size_t)(pbase + m) * H;
        #pragma unroll
        for (int j = 0; j < 4; j++) {
          int n = n0 + wn*64 + j*16 + l16;
          float g = accg[i][j][r];
          float u = accu[i][j][r];
          Hout[prow + n] = f2bf(u * (g / (1.f + expf(-g))));
        }
      }
    }
  }
}

// ---------------- down-projection: out[tok] (+)= scale * (h @ W2^T) ---------
__global__ __launch_bounds__(256, 3) void down_kernel(
    const u16* __restrict__ Hbuf, int K,
    const u16* __restrict__ W2_all,
    float* __restrict__ out,
    const int* __restrict__ tok_of, const float* __restrict__ scale,
    const int* __restrict__ offs, const int* __restrict__ counts,
    const int* __restrict__ desc_e, const int* __restrict__ desc_m,
    int atomic_mode) {
  int e, m0, cnt, pbase;
  if (desc_e) {
    e = desc_e[blockIdx.x];
    if (e < 0) return;
    m0 = desc_m[blockIdx.x];
    cnt = counts[e]; pbase = offs[e];
  } else {
    e = 0; m0 = blockIdx.x * 128; cnt = NTOK; pbase = 0;
  }
  int n0 = blockIdx.y * 128;
  const u16* W2 = W2_all + (size_t)e * D_ * K;

  __shared__ u16 As[128 * LROW];
  __shared__ u16 Bs[128 * LROW];

  int tid  = threadIdx.x;
  int lane = tid & 63, wave = tid >> 6;
  int wm = wave & 1, wn = wave >> 1;
  int l16 = lane & 15, quad = lane >> 4;

  int rs = tid >> 2;
  int cs = (tid & 3) * 8;

  int gm0 = m0 + rs;      if (gm0 >= cnt) gm0 = cnt - 1;
  int gm1 = m0 + rs + 64; if (gm1 >= cnt) gm1 = cnt - 1;
  const u16* pa0 = Hbuf + (size_t)(pbase + gm0) * K + cs;
  const u16* pa1 = Hbuf + (size_t)(pbase + gm1) * K + cs;
  const u16* pb0 = W2 + (size_t)(n0 + rs) * K + cs;
  const u16* pb1 = pb0 + (size_t)64 * K;
  uint4* lA0 = (uint4*)&As[rs*LROW + cs]; uint4* lA1 = (uint4*)&As[(rs+64)*LROW + cs];
  uint4* lB0 = (uint4*)&Bs[rs*LROW + cs]; uint4* lB1 = (uint4*)&Bs[(rs+64)*LROW + cs];

  f32x4 acc[4][4];
  f32x4 zero = {0.f, 0.f, 0.f, 0.f};
  #pragma unroll
  for (int i = 0; i < 4; i++)
    #pragma unroll
    for (int j = 0; j < 4; j++) acc[i][j] = zero;

  uint4 ra0 = *(const uint4*)pa0, ra1 = *(const uint4*)pa1;
  uint4 rb0 = *(const uint4*)pb0, rb1 = *(const uint4*)pb1;

  for (int k0 = 0; k0 < K; k0 += 32) {
    __syncthreads();
    *lA0 = ra0; *lA1 = ra1;
    *lB0 = rb0; *lB1 = rb1;
    __syncthreads();
    if (k0 + 32 < K) {
      pa0 += 32; pa1 += 32; pb0 += 32; pb1 += 32;
      ra0 = *(const uint4*)pa0; ra1 = *(const uint4*)pa1;
      rb0 = *(const uint4*)pb0; rb1 = *(const uint4*)pb1;
    }

    bf16x8 af[4], bfr[4];
    #pragma unroll
    for (int i = 0; i < 4; i++) {
      af[i]  = *(const bf16x8*)&As[(wm*64 + i*16 + l16)*LROW + quad*8];
      bfr[i] = *(const bf16x8*)&Bs[(wn*64 + i*16 + l16)*LROW + quad*8];
    }
    #pragma unroll
    for (int i = 0; i < 4; i++)
      #pragma unroll
      for (int j = 0; j < 4; j++)
        acc[i][j] = __builtin_amdgcn_mfma_f32_16x16x32_bf16(af[i], bfr[j], acc[i][j], 0, 0, 0);
  }

  #pragma unroll
  for (int i = 0; i < 4; i++) {
    #pragma unroll
    for (int r = 0; r < 4; r++) {
      int m = m0 + wm*64 + i*16 + quad*4 + r;
      if (m < cnt) {
        int p   = pbase + m;
        int tok = tok_of ? tok_of[p] : p;
        float sc = scale[p];
        if (atomic_mode) {
          #pragma unroll
          for (int j = 0; j < 4; j++) {
            int n = n0 + wn*64 + j*16 + l16;
            atomicAdd(&out[(size_t)tok * D_ + n], sc * acc[i][j][r]);
          }
        } else {
          #pragma unroll
          for (int j = 0; j < 4; j++) {
            int n = n0 + wn*64 + j*16 + l16;
            out[(size_t)tok * D_ + n] = sc * acc[i][j][r];
          }
        }
      }
    }
  }
}

extern "C" void kernel_launch(void* const* d_in, const int* in_sizes, int n_in,
                              void* d_out, int out_size, void* d_ws, size_t ws_size,
                              hipStream_t stream) {
  const float* x      = (const float*)d_in[0];
  const float* gate_w = (const float*)d_in[1];
  const float* w_gate = (const float*)d_in[2];
  const float* w1     = (const float*)d_in[3];
  const float* w2     = (const float*)d_in[4];
  const float* sh_wg  = (const float*)d_in[5];
  const float* sh_w1  = (const float*)d_in[6];
  const float* sh_w2  = (const float*)d_in[7];
  const float* sh_gw  = (const float*)d_in[8];
  float* out = (float*)d_out;

  char* ws = (char*)d_ws;
  size_t off = 0;
  u16* xb    = (u16*)(ws + off); off += (size_t)NTOK * D_ * 2;
  u16* h_exp = (u16*)(ws + off); off += (size_t)NTOK * TOPK * H_ * 2;
  u16* h_sh  = (u16*)(ws + off); off += (size_t)NTOK * SH_ * 2;
  u16* wb_g  = (u16*)(ws + off); off += (size_t)E_ * H_ * D_ * 2;
  u16* wb_1  = (u16*)(ws + off); off += (size_t)E_ * H_ * D_ * 2;
  u16* wb_2  = (u16*)(ws + off); off += (size_t)E_ * D_ * H_ * 2;
  u16* sb_g  = (u16*)(ws + off); off += (size_t)SH_ * D_ * 2;
  u16* sb_1  = (u16*)(ws + off); off += (size_t)SH_ * D_ * 2;
  u16* sb_2  = (u16*)(ws + off); off += (size_t)D_ * SH_ * 2;
  int*   tok_of = (int*)  (ws + off); off += NTOK * TOPK * 4;
  float* w_of   = (float*)(ws + off); off += NTOK * TOPK * 4;
  float* sg     = (float*)(ws + off); off += NTOK * 4;
  int*   topk_e = (int*)  (ws + off); off += NTOK * TOPK * 4;
  float* topk_w = (float*)(ws + off); off += NTOK * TOPK * 4;
  int*   counts = (int*)  (ws + off); off += 64;
  int*   offs   = (int*)  (ws + off); off += 128;
  int*   fill   = (int*)  (ws + off); off += 64;
  int*   desc_e = (int*)  (ws + off); off += NDESC * 4;
  int*   desc_m = (int*)  (ws + off); off += NDESC * 4;

  hipMemsetAsync(counts, 0, 256, stream);   // counts + offs + fill

  cvt_k<<<dim3(NTOK * D_ / 1024), 256, 0, stream>>>(x, xb);
  cvt_k<<<dim3(E_ * H_ * D_ / 1024), 256, 0, stream>>>(w_gate, wb_g);
  cvt_k<<<dim3(E_ * H_ * D_ / 1024), 256, 0, stream>>>(w1, wb_1);
  cvt_k<<<dim3(E_ * D_ * H_ / 1024), 256, 0, stream>>>(w2, wb_2);
  cvt_k<<<dim3(SH_ * D_ / 1024), 256, 0, stream>>>(sh_wg, sb_g);
  cvt_k<<<dim3(SH_ * D_ / 1024), 256, 0, stream>>>(sh_w1, sb_1);
  cvt_k<<<dim3(D_ * SH_ / 1024), 256, 0, stream>>>(sh_w2, sb_2);

  router_k<<<dim3(NTOK), 64, 0, stream>>>(x, gate_w, sh_gw, topk_e, topk_w, sg, counts);
  scan_k<<<dim3(1), 64, 0, stream>>>(counts, offs, desc_e, desc_m);
  scatter_k<<<dim3((NTOK + 255) / 256), 256, 0, stream>>>(topk_e, topk_w, offs, fill, tok_of, w_of);

  // shared expert first: its down-projection STOREs (covers all of out, no memset)
  up_kernel<<<dim3(NTOK/128, SH_/128), 256, 0, stream>>>(
      xb, sb_g, sb_1, h_sh, SH_, nullptr, nullptr, nullptr, nullptr, nullptr);
  down_kernel<<<dim3(NTOK/128, D_/128), 256, 0, stream>>>(
      h_sh, SH_, sb_2, out, nullptr, sg, nullptr, nullptr, nullptr, nullptr, /*atomic=*/0);

  // routed experts via compact chunk-descriptor grid
  up_kernel<<<dim3(NDESC, H_/128), 256, 0, stream>>>(
      xb, wb_g, wb_1, h_exp, H_, tok_of, offs, counts, desc_e, desc_m);
  down_kernel<<<dim3(NDESC, D_/128), 256, 0, stream>>>(
      h_exp, H_, wb_2, out, tok_of, w_of, offs, counts, desc_e, desc_m, /*atomic=*/1);

  (void)in_sizes; (void)n_in; (void)ws_size;
}

// Round 4
// 559.413 us; speedup vs baseline: 1.9053x; 1.1619x over previous
//
#include <hip/hip_runtime.h>
#include <stdint.h>

#define E_    16
#define TOPK  2
#define D_    1024
#define H_    1024
#define SH_   2048
#define NTOK  4096
#define LROW  40      // LDS row pitch in u16: 32 payload + 8 pad -> only 2-way bank aliasing (free)
#define NDESC 80      // max expert chunks: 8192/128 + 16 partials
#define RTOK  16      // router tokens per block

typedef unsigned short u16;
typedef __attribute__((ext_vector_type(8))) __bf16 bf16x8;
typedef __attribute__((ext_vector_type(4))) float  f32x4;

__device__ __forceinline__ u16 f2bf(float f) {
  union { float f; unsigned int u; } v; v.f = f;
  unsigned int u = v.u;
  return (u16)((u + 0x7fffu + ((u >> 16) & 1u)) >> 16);   // RN-even
}

// ---------------- fp32 -> bf16 converter ----------------
__global__ __launch_bounds__(256) void cvt_k(const float* __restrict__ src,
                                             u16* __restrict__ dst) {
  int i = blockIdx.x * 256 + threadIdx.x;      // one float4 per thread
  float4 f = ((const float4*)src)[i];
  ushort4 o; o.x = f2bf(f.x); o.y = f2bf(f.y); o.z = f2bf(f.z); o.w = f2bf(f.w);
  ((ushort4*)dst)[i] = o;
}

// ---------------- router v2: 16 tokens/block, thread=(expert,token), fp32 ----
// gate_w streamed from L1/L2 (independent float4 loads => deep memory-level
// parallelism, the R3 kernel's missing ingredient); x chunk staged in LDS.
__global__ __launch_bounds__(256) void router_k(
    const float* __restrict__ x, const float* __restrict__ gate_w,
    const float* __restrict__ shared_gate_w,
    int* __restrict__ topk_e, float* __restrict__ topk_w,
    float* __restrict__ sg, int* __restrict__ counts) {
  __shared__ float xs[RTOK][132];   // +4 pad: rows offset by 4 banks
  __shared__ float lg[RTOK][16];
  __shared__ float sgp[RTOK][16];

  int tid = threadIdx.x;
  int e   = tid >> 4;               // 0..15
  int tt  = tid & 15;               // 0..15
  int t0  = blockIdx.x * RTOK;

  float acc = 0.f, sga = 0.f;
  for (int c = 0; c < D_; c += 128) {
    __syncthreads();                // xs reuse from previous chunk done
    #pragma unroll
    for (int i = 0; i < 2; i++) {
      int f = i * 256 + tid;        // 0..511 float4 units, fully coalesced
      int r = f >> 5, c4 = f & 31;
      *(float4*)&xs[r][c4 * 4] =
          *(const float4*)&x[(size_t)(t0 + r) * D_ + c + c4 * 4];
    }
    __syncthreads();
    const float* gw = &gate_w[(size_t)e * D_ + c];
    #pragma unroll
    for (int d4 = 0; d4 < 32; d4++) {
      float4 g  = *(const float4*)&gw[d4 * 4];
      float4 xv = *(const float4*)&xs[tt][d4 * 4];
      acc += xv.x * g.x + xv.y * g.y + xv.z * g.z + xv.w * g.w;
    }
    // shared-gate partial: this thread covers d in [e*8, e*8+8)
    #pragma unroll
    for (int j = 0; j < 8; j += 4) {
      float4 s  = *(const float4*)&shared_gate_w[c + e * 8 + j];
      float4 xv = *(const float4*)&xs[tt][e * 8 + j];
      sga += xv.x * s.x + xv.y * s.y + xv.z * s.z + xv.w * s.w;
    }
  }
  lg[tt][e]  = acc;
  sgp[tt][e] = sga;
  __syncthreads();

  if (tid < RTOK) {
    int t = t0 + tid;
    float l[16];
    #pragma unroll
    for (int k = 0; k < 16; k++) l[k] = lg[tid][k];
    int i0 = 0; float l0 = l[0];
    for (int k = 1; k < 16; k++) if (l[k] > l0) { l0 = l[k]; i0 = k; }
    int i1 = -1; float l1 = -3.4e38f;
    for (int k = 0; k < 16; k++) if (k != i0 && l[k] > l1) { l1 = l[k]; i1 = k; }
    float w0 = 1.f / (1.f + expf(l1 - l0));   // == p0/(p0+p1)
    float s = 0.f;
    #pragma unroll
    for (int k = 0; k < 16; k++) s += sgp[tid][k];
    topk_e[2*t] = i0; topk_e[2*t+1] = i1;
    topk_w[2*t] = w0; topk_w[2*t+1] = 1.f - w0;
    sg[t] = 1.f / (1.f + expf(-s));
    atomicAdd(&counts[i0], 1);
    atomicAdd(&counts[i1], 1);
  }
}

// prefix scan + compact chunk-descriptor table (chunk -> expert, m0)
__global__ void scan_k(const int* __restrict__ counts, int* __restrict__ offs,
                       int* __restrict__ desc_e, int* __restrict__ desc_m) {
  if (threadIdx.x == 0) {
    int s = 0, n = 0;
    for (int e = 0; e < E_; e++) {
      offs[e] = s;
      for (int m0 = 0; m0 < counts[e]; m0 += 128) {
        desc_e[n] = e; desc_m[n] = m0; n++;
      }
      s += counts[e];
    }
    offs[E_] = s;
    for (; n < NDESC; n++) { desc_e[n] = -1; desc_m[n] = 0; }
  }
}

__global__ __launch_bounds__(256) void scatter_k(
    const int* __restrict__ topk_e, const float* __restrict__ topk_w,
    const int* __restrict__ offs, int* __restrict__ fill,
    int* __restrict__ tok_of, float* __restrict__ w_of) {
  int t = blockIdx.x * 256 + threadIdx.x;
  if (t >= NTOK) return;
  for (int k = 0; k < TOPK; k++) {
    int e = topk_e[2*t+k];
    int p = atomicAdd(&fill[e], 1);
    int slot = offs[e] + p;
    tok_of[slot] = t;
    w_of[slot]   = topk_w[2*t+k];
  }
}

// ---------------- fused gated up-projection: h = (x@W1^T) * silu(x@Wg^T) ----
__global__ __launch_bounds__(256, 2) void up_kernel(
    const u16* __restrict__ Xb,
    const u16* __restrict__ Wg_all, const u16* __restrict__ W1_all,
    u16* __restrict__ Hout, int H,
    const int* __restrict__ tok_of,
    const int* __restrict__ offs, const int* __restrict__ counts,
    const int* __restrict__ desc_e, const int* __restrict__ desc_m) {
  int e, m0, cnt, pbase;
  if (desc_e) {
    e = desc_e[blockIdx.x];
    if (e < 0) return;
    m0 = desc_m[blockIdx.x];
    cnt = counts[e]; pbase = offs[e];
  } else {
    e = 0; m0 = blockIdx.x * 128; cnt = NTOK; pbase = 0;
  }
  int n0 = blockIdx.y * 128;
  const u16* Wg = Wg_all + (size_t)e * H * D_;
  const u16* W1 = W1_all + (size_t)e * H * D_;

  __shared__ u16 As[128 * LROW];
  __shared__ u16 Gs[128 * LROW];
  __shared__ u16 Us[128 * LROW];

  int tid  = threadIdx.x;
  int lane = tid & 63, wave = tid >> 6;
  int wm = wave & 1, wn = wave >> 1;
  int l16 = lane & 15, quad = lane >> 4;

  int rs = tid >> 2;          // staging row 0..63 (and +64)
  int cs = (tid & 3) * 8;     // staging col (elements)

  int gm0 = m0 + rs;      if (gm0 >= cnt) gm0 = cnt - 1;
  int gm1 = m0 + rs + 64; if (gm1 >= cnt) gm1 = cnt - 1;
  int tok0 = tok_of ? tok_of[pbase + gm0] : gm0;
  int tok1 = tok_of ? tok_of[pbase + gm1] : gm1;
  const u16* pa0 = Xb + (size_t)tok0 * D_ + cs;
  const u16* pa1 = Xb + (size_t)tok1 * D_ + cs;
  const u16* pg0 = Wg + (size_t)(n0 + rs) * D_ + cs;
  const u16* pg1 = pg0 + (size_t)64 * D_;
  const u16* pu0 = W1 + (size_t)(n0 + rs) * D_ + cs;
  const u16* pu1 = pu0 + (size_t)64 * D_;
  uint4* lA0 = (uint4*)&As[rs*LROW + cs]; uint4* lA1 = (uint4*)&As[(rs+64)*LROW + cs];
  uint4* lG0 = (uint4*)&Gs[rs*LROW + cs]; uint4* lG1 = (uint4*)&Gs[(rs+64)*LROW + cs];
  uint4* lU0 = (uint4*)&Us[rs*LROW + cs]; uint4* lU1 = (uint4*)&Us[(rs+64)*LROW + cs];

  f32x4 accg[4][4], accu[4][4];
  f32x4 zero = {0.f, 0.f, 0.f, 0.f};
  #pragma unroll
  for (int i = 0; i < 4; i++)
    #pragma unroll
    for (int j = 0; j < 4; j++) { accg[i][j] = zero; accu[i][j] = zero; }

  uint4 ra0 = *(const uint4*)pa0, ra1 = *(const uint4*)pa1;
  uint4 rg0 = *(const uint4*)pg0, rg1 = *(const uint4*)pg1;
  uint4 ru0 = *(const uint4*)pu0, ru1 = *(const uint4*)pu1;

  for (int k0 = 0; k0 < D_; k0 += 32) {
    __syncthreads();
    *lA0 = ra0; *lA1 = ra1;
    *lG0 = rg0; *lG1 = rg1;
    *lU0 = ru0; *lU1 = ru1;
    __syncthreads();
    if (k0 + 32 < D_) {
      pa0 += 32; pa1 += 32; pg0 += 32; pg1 += 32; pu0 += 32; pu1 += 32;
      ra0 = *(const uint4*)pa0; ra1 = *(const uint4*)pa1;
      rg0 = *(const uint4*)pg0; rg1 = *(const uint4*)pg1;
      ru0 = *(const uint4*)pu0; ru1 = *(const uint4*)pu1;
    }

    bf16x8 af[4], gf[4], uf[4];
    #pragma unroll
    for (int i = 0; i < 4; i++) {
      af[i] = *(const bf16x8*)&As[(wm*64 + i*16 + l16)*LROW + quad*8];
      gf[i] = *(const bf16x8*)&Gs[(wn*64 + i*16 + l16)*LROW + quad*8];
      uf[i] = *(const bf16x8*)&Us[(wn*64 + i*16 + l16)*LROW + quad*8];
    }
    #pragma unroll
    for (int i = 0; i < 4; i++)
      #pragma unroll
      for (int j = 0; j < 4; j++) {
        accg[i][j] = __builtin_amdgcn_mfma_f32_16x16x32_bf16(af[i], gf[j], accg[i][j], 0, 0, 0);
        accu[i][j] = __builtin_amdgcn_mfma_f32_16x16x32_bf16(af[i], uf[j], accu[i][j], 0, 0, 0);
      }
  }

  // epilogue: h = u * silu(g)  (C/D map: col=lane&15, row=quad*4+reg — verified)
  #pragma unroll
  for (int i = 0; i < 4; i++) {
    #pragma unroll
    for (int r = 0; r < 4; r++) {
      int m = m0 + wm*64 + i*16 + quad*4 + r;
      if (m < cnt) {
        size_t prow = (size_t)(pbase + m) * H;
        #pragma unroll
        for (int j = 0; j < 4; j++) {
          int n = n0 + wn*64 + j*16 + l16;
          float g = accg[i][j][r];
          float u = accu[i][j][r];
          Hout[prow + n] = f2bf(u * (g / (1.f + expf(-g))));
        }
      }
    }
  }
}

// ---------------- down-projection: out[tok] (+)= scale * (h @ W2^T) ---------
__global__ __launch_bounds__(256, 3) void down_kernel(
    const u16* __restrict__ Hbuf, int K,
    const u16* __restrict__ W2_all,
    float* __restrict__ out,
    const int* __restrict__ tok_of, const float* __restrict__ scale,
    const int* __restrict__ offs, const int* __restrict__ counts,
    const int* __restrict__ desc_e, const int* __restrict__ desc_m,
    int atomic_mode) {
  int e, m0, cnt, pbase;
  if (desc_e) {
    e = desc_e[blockIdx.x];
    if (e < 0) return;
    m0 = desc_m[blockIdx.x];
    cnt = counts[e]; pbase = offs[e];
  } else {
    e = 0; m0 = blockIdx.x * 128; cnt = NTOK; pbase = 0;
  }
  int n0 = blockIdx.y * 128;
  const u16* W2 = W2_all + (size_t)e * D_ * K;

  __shared__ u16 As[128 * LROW];
  __shared__ u16 Bs[128 * LROW];

  int tid  = threadIdx.x;
  int lane = tid & 63, wave = tid >> 6;
  int wm = wave & 1, wn = wave >> 1;
  int l16 = lane & 15, quad = lane >> 4;

  int rs = tid >> 2;
  int cs = (tid & 3) * 8;

  int gm0 = m0 + rs;      if (gm0 >= cnt) gm0 = cnt - 1;
  int gm1 = m0 + rs + 64; if (gm1 >= cnt) gm1 = cnt - 1;
  const u16* pa0 = Hbuf + (size_t)(pbase + gm0) * K + cs;
  const u16* pa1 = Hbuf + (size_t)(pbase + gm1) * K + cs;
  const u16* pb0 = W2 + (size_t)(n0 + rs) * K + cs;
  const u16* pb1 = pb0 + (size_t)64 * K;
  uint4* lA0 = (uint4*)&As[rs*LROW + cs]; uint4* lA1 = (uint4*)&As[(rs+64)*LROW + cs];
  uint4* lB0 = (uint4*)&Bs[rs*LROW + cs]; uint4* lB1 = (uint4*)&Bs[(rs+64)*LROW + cs];

  f32x4 acc[4][4];
  f32x4 zero = {0.f, 0.f, 0.f, 0.f};
  #pragma unroll
  for (int i = 0; i < 4; i++)
    #pragma unroll
    for (int j = 0; j < 4; j++) acc[i][j] = zero;

  uint4 ra0 = *(const uint4*)pa0, ra1 = *(const uint4*)pa1;
  uint4 rb0 = *(const uint4*)pb0, rb1 = *(const uint4*)pb1;

  for (int k0 = 0; k0 < K; k0 += 32) {
    __syncthreads();
    *lA0 = ra0; *lA1 = ra1;
    *lB0 = rb0; *lB1 = rb1;
    __syncthreads();
    if (k0 + 32 < K) {
      pa0 += 32; pa1 += 32; pb0 += 32; pb1 += 32;
      ra0 = *(const uint4*)pa0; ra1 = *(const uint4*)pa1;
      rb0 = *(const uint4*)pb0; rb1 = *(const uint4*)pb1;
    }

    bf16x8 af[4], bfr[4];
    #pragma unroll
    for (int i = 0; i < 4; i++) {
      af[i]  = *(const bf16x8*)&As[(wm*64 + i*16 + l16)*LROW + quad*8];
      bfr[i] = *(const bf16x8*)&Bs[(wn*64 + i*16 + l16)*LROW + quad*8];
    }
    #pragma unroll
    for (int i = 0; i < 4; i++)
      #pragma unroll
      for (int j = 0; j < 4; j++)
        acc[i][j] = __builtin_amdgcn_mfma_f32_16x16x32_bf16(af[i], bfr[j], acc[i][j], 0, 0, 0);
  }

  #pragma unroll
  for (int i = 0; i < 4; i++) {
    #pragma unroll
    for (int r = 0; r < 4; r++) {
      int m = m0 + wm*64 + i*16 + quad*4 + r;
      if (m < cnt) {
        int p   = pbase + m;
        int tok = tok_of ? tok_of[p] : p;
        float sc = scale[p];
        if (atomic_mode) {
          #pragma unroll
          for (int j = 0; j < 4; j++) {
            int n = n0 + wn*64 + j*16 + l16;
            atomicAdd(&out[(size_t)tok * D_ + n], sc * acc[i][j][r]);
          }
        } else {
          #pragma unroll
          for (int j = 0; j < 4; j++) {
            int n = n0 + wn*64 + j*16 + l16;
            out[(size_t)tok * D_ + n] = sc * acc[i][j][r];
          }
        }
      }
    }
  }
}

extern "C" void kernel_launch(void* const* d_in, const int* in_sizes, int n_in,
                              void* d_out, int out_size, void* d_ws, size_t ws_size,
                              hipStream_t stream) {
  const float* x      = (const float*)d_in[0];
  const float* gate_w = (const float*)d_in[1];
  const float* w_gate = (const float*)d_in[2];
  const float* w1     = (const float*)d_in[3];
  const float* w2     = (const float*)d_in[4];
  const float* sh_wg  = (const float*)d_in[5];
  const float* sh_w1  = (const float*)d_in[6];
  const float* sh_w2  = (const float*)d_in[7];
  const float* sh_gw  = (const float*)d_in[8];
  float* out = (float*)d_out;

  char* ws = (char*)d_ws;
  size_t off = 0;
  u16* xb    = (u16*)(ws + off); off += (size_t)NTOK * D_ * 2;
  u16* h_exp = (u16*)(ws + off); off += (size_t)NTOK * TOPK * H_ * 2;
  u16* h_sh  = (u16*)(ws + off); off += (size_t)NTOK * SH_ * 2;
  u16* wb_g  = (u16*)(ws + off); off += (size_t)E_ * H_ * D_ * 2;
  u16* wb_1  = (u16*)(ws + off); off += (size_t)E_ * H_ * D_ * 2;
  u16* wb_2  = (u16*)(ws + off); off += (size_t)E_ * D_ * H_ * 2;
  u16* sb_g  = (u16*)(ws + off); off += (size_t)SH_ * D_ * 2;
  u16* sb_1  = (u16*)(ws + off); off += (size_t)SH_ * D_ * 2;
  u16* sb_2  = (u16*)(ws + off); off += (size_t)D_ * SH_ * 2;
  int*   tok_of = (int*)  (ws + off); off += NTOK * TOPK * 4;
  float* w_of   = (float*)(ws + off); off += NTOK * TOPK * 4;
  float* sg     = (float*)(ws + off); off += NTOK * 4;
  int*   topk_e = (int*)  (ws + off); off += NTOK * TOPK * 4;
  float* topk_w = (float*)(ws + off); off += NTOK * TOPK * 4;
  int*   counts = (int*)  (ws + off); off += 64;
  int*   offs   = (int*)  (ws + off); off += 128;
  int*   fill   = (int*)  (ws + off); off += 64;
  int*   desc_e = (int*)  (ws + off); off += NDESC * 4;
  int*   desc_m = (int*)  (ws + off); off += NDESC * 4;

  hipMemsetAsync(counts, 0, 256, stream);   // counts + offs + fill

  cvt_k<<<dim3(NTOK * D_ / 1024), 256, 0, stream>>>(x, xb);
  cvt_k<<<dim3(E_ * H_ * D_ / 1024), 256, 0, stream>>>(w_gate, wb_g);
  cvt_k<<<dim3(E_ * H_ * D_ / 1024), 256, 0, stream>>>(w1, wb_1);
  cvt_k<<<dim3(E_ * D_ * H_ / 1024), 256, 0, stream>>>(w2, wb_2);
  cvt_k<<<dim3(SH_ * D_ / 1024), 256, 0, stream>>>(sh_wg, sb_g);
  cvt_k<<<dim3(SH_ * D_ / 1024), 256, 0, stream>>>(sh_w1, sb_1);
  cvt_k<<<dim3(D_ * SH_ / 1024), 256, 0, stream>>>(sh_w2, sb_2);

  router_k<<<dim3(NTOK / RTOK), 256, 0, stream>>>(x, gate_w, sh_gw, topk_e, topk_w, sg, counts);
  scan_k<<<dim3(1), 64, 0, stream>>>(counts, offs, desc_e, desc_m);
  scatter_k<<<dim3((NTOK + 255) / 256), 256, 0, stream>>>(topk_e, topk_w, offs, fill, tok_of, w_of);

  // shared expert first: its down-projection STOREs (covers all of out, no memset)
  up_kernel<<<dim3(NTOK/128, SH_/128), 256, 0, stream>>>(
      xb, sb_g, sb_1, h_sh, SH_, nullptr, nullptr, nullptr, nullptr, nullptr);
  down_kernel<<<dim3(NTOK/128, D_/128), 256, 0, stream>>>(
      h_sh, SH_, sb_2, out, nullptr, sg, nullptr, nullptr, nullptr, nullptr, /*atomic=*/0);

  // routed experts via compact chunk-descriptor grid
  up_kernel<<<dim3(NDESC, H_/128), 256, 0, stream>>>(
      xb, wb_g, wb_1, h_exp, H_, tok_of, offs, counts, desc_e, desc_m);
  down_kernel<<<dim3(NDESC, D_/128), 256, 0, stream>>>(
      h_exp, H_, wb_2, out, tok_of, w_of, offs, counts, desc_e, desc_m, /*atomic=*/1);

  (void)in_sizes; (void)n_in; (void)ws_size;
}